// Round 1
// baseline (7365.793 us; speedup 1.0000x reference)
//
#include <hip/hip_runtime.h>
#include <math.h>

#define B_ 128
#define N_ 128
#define T_ 256
#define H_ 256
#define D_ 50

// K layout for tree GEMV: [c(256) | h(256) | th(50) + pad2] = 564 = 141*4
#define KT4 141
// tracking K: 768 = 192*4
#define KW4 192
// Whh K: 52 = 13*4
#define KH4 13

// ---- workspace layout (float element offsets) ----
#define OFF_SH   0u                      // stack_h: B*(T+1)*H = 8421376
#define OFF_SC   8421376u                // stack_c: 8421376
#define OFF_WP   16842752u               // packed tree W: 141*1024*4 = 577536
#define OFF_WIHP 17420288u               // packed Wih: 192*200*4 = 153600
#define OFF_WHHP 17573888u               // packed Whh: 13*200*4 = 10400
#define OFF_BCOL 17584288u               // per-column tree bias: 1024
#define OFF_BTRK 17585312u               // bih+bhh: 200
#define OFF_IDX  17585512u               // int region: B*T*3 = 98304 ints
// total = 17683816 floats = ~67.5 MiB

__device__ __forceinline__ float sigf(float x) { return 1.0f / (1.0f + expf(-x)); }

__device__ __forceinline__ void fma4(float4& a, const float4 w, const float4 v) {
    a.x = fmaf(w.x, v.x, a.x);
    a.y = fmaf(w.y, v.y, a.y);
    a.z = fmaf(w.z, v.z, a.z);
    a.w = fmaf(w.w, v.w, a.w);
}

// ------------------------------------------------------------------
// Precompute sp1/sp2/bp per (b, step): queue dynamics depend only on
// transitions, not on any computed value.
// ------------------------------------------------------------------
__global__ void sim_idx(const int* __restrict__ trans, int* __restrict__ idx) {
    int b = blockIdx.x * blockDim.x + threadIdx.x;
    if (b >= B_) return;
    int queue[T_ + 1];
    int qlen = 0, bptr = 0;
    for (int st = 0; st < T_; ++st) {
        int tr = trans[b * T_ + st];
        int mask = (tr >= 1);
        int sp1 = (qlen >= 1) ? queue[qlen - 1] : 0;
        int sp2 = (qlen >= 2) ? queue[qlen - 2] : 0;
        int bp = bptr < (N_ - 1) ? bptr : (N_ - 1);
        int o = (b * T_ + st) * 3;
        idx[o] = sp1; idx[o + 1] = sp2; idx[o + 2] = bp;
        int qlen2 = mask ? (qlen - 2 > 0 ? qlen - 2 : 0) : qlen;
        queue[qlen2] = st + 1;
        qlen = qlen2 + 1;
        bptr += mask ? 0 : 1;
    }
}

// ------------------------------------------------------------------
// Pack tree weights: W'[k4][c][4], c = 4*j + g.
// gate g: 0=i (Ul0,Ur0,Wx0,b0)  1=o (Ul2,Ur2,Wx2,b2)
//         2=f (Ul1,Ur1,Wx2!,b1) 3=u (Ul3,Ur3,Wx3,b3)
// rows: k<256 -> Ul (applied to c-part), k<512 -> Ur (h-part), k<562 -> Wx (th), pad 0
// ------------------------------------------------------------------
__global__ void pack_tree(const float* __restrict__ Ul, const float* __restrict__ Ur,
                          const float* __restrict__ Wx, float* __restrict__ Wp) {
    int i = blockIdx.x * blockDim.x + threadIdx.x;
    if (i >= KT4 * 1024) return;
    int k4 = i >> 10, c = i & 1023, j = c >> 2, g = c & 3;
    const int gl[4] = {0, 2, 1, 3};
    const int gx[4] = {0, 2, 2, 3};
    float tmp[4];
    for (int kk = 0; kk < 4; ++kk) {
        int k = k4 * 4 + kk;
        float v;
        if (k < 256)      v = Ul[(gl[g] * H_ + j) * H_ + k];
        else if (k < 512) v = Ur[(gl[g] * H_ + j) * H_ + (k - 256)];
        else {
            int d = k - 512;
            v = (d < D_) ? Wx[(gx[g] * H_ + j) * D_ + d] : 0.0f;
        }
        tmp[kk] = v;
    }
    ((float4*)Wp)[i] = make_float4(tmp[0], tmp[1], tmp[2], tmp[3]);
}

// Pack Wih [192][200][4], Whh [13][200][4] (pad m>=50 with 0), bcol[1024], btrk[200]
__global__ void pack_small(const float* __restrict__ Wih, const float* __restrict__ Whh,
                           const float* __restrict__ bias4,
                           const float* __restrict__ bih, const float* __restrict__ bhh,
                           float* __restrict__ Wihp, float* __restrict__ Whhp,
                           float* __restrict__ bcol, float* __restrict__ btrk) {
    int i = blockIdx.x * blockDim.x + threadIdx.x;
    if (i < KW4 * 200) {
        int k4 = i / 200, d = i % 200;
        float tmp[4];
        for (int kk = 0; kk < 4; ++kk) tmp[kk] = Wih[d * 768 + k4 * 4 + kk];
        ((float4*)Wihp)[i] = make_float4(tmp[0], tmp[1], tmp[2], tmp[3]);
    } else if (i < KW4 * 200 + KH4 * 200) {
        int ii = i - KW4 * 200;
        int m4 = ii / 200, d = ii % 200;
        float tmp[4];
        for (int kk = 0; kk < 4; ++kk) {
            int m = m4 * 4 + kk;
            tmp[kk] = (m < D_) ? Whh[d * D_ + m] : 0.0f;
        }
        ((float4*)Whhp)[ii] = make_float4(tmp[0], tmp[1], tmp[2], tmp[3]);
    } else if (i < KW4 * 200 + KH4 * 200 + 1024) {
        int c = i - (KW4 * 200 + KH4 * 200);
        int j = c >> 2, g = c & 3;
        const int gb[4] = {0, 2, 1, 3};
        bcol[c] = bias4[gb[g] * H_ + j];
    } else if (i < KW4 * 200 + KH4 * 200 + 1024 + 200) {
        int d = i - (KW4 * 200 + KH4 * 200 + 1024);
        btrk[d] = bih[d] + bhh[d];
    }
}

// ------------------------------------------------------------------
// Main: one 1024-thread workgroup per batch element, loops T steps.
// Zero grid syncs; weights stream from (XCD-local) L2.
// ------------------------------------------------------------------
__global__ __launch_bounds__(1024, 1)
void trnn_main(const float* __restrict__ tokens_h, const float* __restrict__ tokens_c,
               const int* __restrict__ trans,
               const float* __restrict__ th0, const float* __restrict__ tc0,
               float* __restrict__ ws, const int* __restrict__ idx,
               float* __restrict__ out) {
    const int b = blockIdx.x;
    const int tid = threadIdx.x;

    float* stack_h = ws + OFF_SH + (size_t)b * (T_ + 1) * H_;
    float* stack_c = ws + OFF_SC + (size_t)b * (T_ + 1) * H_;
    const float4* Wp4   = (const float4*)(ws + OFF_WP);
    const float4* Wihp4 = (const float4*)(ws + OFF_WIHP);
    const float4* Whhp4 = (const float4*)(ws + OFF_WHHP);
    const float* bcol = ws + OFF_BCOL;
    const float* btrk = ws + OFF_BTRK;

    __shared__ __align__(16) float hs1[H_], cs1[H_], hs2[H_], cs2[H_], bth[H_];
    __shared__ __align__(16) float th_l[52], tc_l[52];
    __shared__ float g_l[200];
    __shared__ __align__(16) float act1[1024], act2[1024];

    if (tid < 52) {
        th_l[tid] = (tid < D_) ? th0[b * D_ + tid] : 0.0f;
        tc_l[tid] = (tid < D_) ? tc0[b * D_ + tid] : 0.0f;
    }
    if (tid < H_) { stack_h[tid] = 0.0f; stack_c[tid] = 0.0f; }  // zero stack row 0
    __syncthreads();

    const float bias_c = bcol[tid];

    for (int t = 1; t <= T_; ++t) {
        const int st = t - 1;
        const int i3 = (b * T_ + st) * 3;
        const int sp1 = idx[i3], sp2 = idx[i3 + 1], bp = idx[i3 + 2];

        // ---- stage gathered rows into LDS ----
        if (tid < 256) {
            hs1[tid] = stack_h[sp1 * H_ + tid];
            bth[tid] = tokens_h[((size_t)b * N_ + bp) * H_ + tid];
        } else if (tid < 512) {
            int j = tid - 256; cs1[j] = stack_c[sp1 * H_ + j];
        } else if (tid < 768) {
            int j = tid - 512; hs2[j] = stack_h[sp2 * H_ + j];
        } else {
            int j = tid - 768; cs2[j] = stack_c[sp2 * H_ + j];
        }
        __syncthreads();

        // ---- tracking LSTM gates: [bt_h,h1,h2]@Wih.T + th@Whh.T + (bih+bhh) ----
        if (tid < 200) {
            float4 a = make_float4(btrk[tid], 0.0f, 0.0f, 0.0f);
            #pragma unroll 4
            for (int k4 = 0; k4 < 64; ++k4)
                fma4(a, Wihp4[k4 * 200 + tid], ((const float4*)bth)[k4]);
            #pragma unroll 4
            for (int k4 = 64; k4 < 128; ++k4)
                fma4(a, Wihp4[k4 * 200 + tid], ((const float4*)hs1)[k4 - 64]);
            #pragma unroll 4
            for (int k4 = 128; k4 < 192; ++k4)
                fma4(a, Wihp4[k4 * 200 + tid], ((const float4*)hs2)[k4 - 128]);
            #pragma unroll
            for (int m4 = 0; m4 < KH4; ++m4)
                fma4(a, Whhp4[m4 * 200 + tid], ((const float4*)th_l)[m4]);
            g_l[tid] = a.x + a.y + a.z + a.w;
        }
        __syncthreads();

        // ---- th/tc update (torch gate order i,f,g,o) ----
        if (tid < D_) {
            float gi = g_l[tid], gf = g_l[50 + tid], gg = g_l[100 + tid], go = g_l[150 + tid];
            float c = fmaf(sigf(gf), tc_l[tid], sigf(gi) * tanhf(gg));
            tc_l[tid] = c;
            th_l[tid] = sigf(go) * tanhf(c);
        }
        __syncthreads();

        // ---- tree pre-activations: both calls share weight columns ----
        {
            float4 a1 = make_float4(bias_c, 0.0f, 0.0f, 0.0f);
            float4 a2 = make_float4(bias_c, 0.0f, 0.0f, 0.0f);
            #pragma unroll 2
            for (int k4 = 0; k4 < 64; ++k4) {
                float4 w = Wp4[(size_t)k4 * 1024 + tid];
                fma4(a1, w, ((const float4*)cs1)[k4]);
                fma4(a2, w, ((const float4*)cs2)[k4]);
            }
            #pragma unroll 2
            for (int k4 = 64; k4 < 128; ++k4) {
                float4 w = Wp4[(size_t)k4 * 1024 + tid];
                fma4(a1, w, ((const float4*)hs1)[k4 - 64]);
                fma4(a2, w, ((const float4*)hs2)[k4 - 64]);
            }
            #pragma unroll
            for (int k4 = 128; k4 < KT4; ++k4) {
                float4 w = Wp4[(size_t)k4 * 1024 + tid];
                float4 v = ((const float4*)th_l)[k4 - 128];
                fma4(a1, w, v);
                fma4(a2, w, v);
            }
            float p1 = a1.x + a1.y + a1.z + a1.w;
            float p2 = a2.x + a2.y + a2.z + a2.w;
            float r1, r2;
            if ((tid & 3) == 3) { r1 = tanhf(p1); r2 = tanhf(p2); }
            else               { r1 = sigf(p1);  r2 = sigf(p2);  }
            act1[tid] = r1;
            act2[tid] = r2;
        }
        __syncthreads();

        // ---- combine + stack write ----
        if (tid < 256) {
            const int j = tid;
            float i1 = act1[4 * j], o1 = act1[4 * j + 1], f1 = act1[4 * j + 2], u1 = act1[4 * j + 3];
            float i2 = act2[4 * j], o2 = act2[4 * j + 1], f2 = act2[4 * j + 2], u2 = act2[4 * j + 3];
            // call1: c = i*u + f*c2 + f*h2 ; call2: c = i*u + f*c2 + f*h1
            float cc1 = fmaf(i1, u1, f1 * (cs2[j] + hs2[j]));
            float cc2 = fmaf(i2, u2, f2 * (cs2[j] + hs1[j]));
            float hh1 = o1 * tanhf(cc1);
            float hh2 = o2 * tanhf(cc2);
            int tr = trans[b * T_ + st];
            float nh, nc;
            if (tr == 0) {
                nh = bth[j];
                nc = tokens_c[((size_t)b * N_ + bp) * H_ + j];
            } else if (tr == 1) { nh = hh1; nc = cc1; }
            else                { nh = hh2; nc = cc2; }
            stack_h[t * H_ + j] = nh;
            stack_c[t * H_ + j] = nc;
            if (t == T_) out[b * H_ + j] = nh;
        }
        __syncthreads();
    }
}

extern "C" void kernel_launch(void* const* d_in, const int* in_sizes, int n_in,
                              void* d_out, int out_size, void* d_ws, size_t ws_size,
                              hipStream_t stream) {
    (void)in_sizes; (void)n_in; (void)out_size; (void)ws_size;
    const float* tokens_h = (const float*)d_in[0];
    const float* tokens_c = (const float*)d_in[1];
    const int*   trans    = (const int*)d_in[2];
    const float* th0      = (const float*)d_in[3];
    const float* tc0      = (const float*)d_in[4];
    const float* Wx       = (const float*)d_in[5];
    const float* Ul       = (const float*)d_in[6];
    const float* Ur       = (const float*)d_in[7];
    const float* bias4    = (const float*)d_in[8];
    const float* Wih      = (const float*)d_in[9];
    const float* Whh      = (const float*)d_in[10];
    const float* bih      = (const float*)d_in[11];
    const float* bhh      = (const float*)d_in[12];

    float* ws = (float*)d_ws;
    float* Wp   = ws + OFF_WP;
    float* Wihp = ws + OFF_WIHP;
    float* Whhp = ws + OFF_WHHP;
    float* bcol = ws + OFF_BCOL;
    float* btrk = ws + OFF_BTRK;
    int*   idx  = (int*)(ws + OFF_IDX);

    hipLaunchKernelGGL(sim_idx, dim3(1), dim3(128), 0, stream, trans, idx);
    hipLaunchKernelGGL(pack_tree, dim3((KT4 * 1024 + 255) / 256), dim3(256), 0, stream,
                       Ul, Ur, Wx, Wp);
    hipLaunchKernelGGL(pack_small, dim3((KW4 * 200 + KH4 * 200 + 1024 + 200 + 255) / 256),
                       dim3(256), 0, stream,
                       Wih, Whh, bias4, bih, bhh, Wihp, Whhp, bcol, btrk);
    hipLaunchKernelGGL(trnn_main, dim3(B_), dim3(1024), 0, stream,
                       tokens_h, tokens_c, trans, th0, tc0, ws, idx, (float*)d_out);
}

// Round 2
// 4083.544 us; speedup vs baseline: 1.8038x; 1.8038x over previous
//
#include <hip/hip_runtime.h>
#include <hip/hip_fp16.h>
#include <math.h>
#include <string.h>

#define B_ 128
#define N_ 128
#define T_ 256
#define H_ 256
#define D_ 50

// tree GEMV: K rows 576 (72 k8-chunks): [c 0..255 | h 256..511 | th 512..561 | pad..575]
//            1024 global cols, 512 per WG (pairwise split)
// tracking:  K rows 832 (104 k8): [bt_h 0..255 | h1 256..511 | h2 512..767 | th 768..817 | pad..831]
#define TREE_K8 72
#define TRK_K8  104

// ---- workspace layout (float element offsets) ----
#define OFF_SH   0u             // stack_h: B*(T+1)*H = 8421376
#define OFF_SC   8421376u       // stack_c: 8421376
#define OFF_PW   16842752u      // tree weights f16: 73728 uint4 = 294912 floats
#define OFF_WTRK 17137664u      // tracking weights f16: 20800 uint4 = 83200 floats
#define OFF_BCOL 17220864u      // 1024
#define OFF_BTRK 17221888u      // 200
#define OFF_FLAG 17222088u      // int x B*T*2 = 65536
#define OFF_IDX  17287624u      // int x B*T*3 = 98304
// end: 17385928 floats (~66.3 MiB) -- round-0 used more, so ws_size suffices

__device__ __forceinline__ float sigf(float x) { return 1.0f / (1.0f + expf(-x)); }

__device__ __forceinline__ float2 h2f(unsigned u) {
    __half2 h;
    memcpy(&h, &u, 4);
    return __half22float2(h);
}

// coherent-point (agent-scope) relaxed load/store: bypass stale caches, no cache invalidates
__device__ __forceinline__ float aload(const float* p) {
    int v = __hip_atomic_load((const int*)p, __ATOMIC_RELAXED, __HIP_MEMORY_SCOPE_AGENT);
    return __int_as_float(v);
}
__device__ __forceinline__ void astore(float* p, float x) {
    __hip_atomic_store((int*)p, __float_as_int(x), __ATOMIC_RELAXED, __HIP_MEMORY_SCOPE_AGENT);
}

// ------------------------------------------------------------------
// queue/bptr trajectory depends only on transitions: precompute sp1/sp2/bp
// ------------------------------------------------------------------
__global__ void sim_idx(const int* __restrict__ trans, int* __restrict__ idx) {
    int b = blockIdx.x * blockDim.x + threadIdx.x;
    if (b >= B_) return;
    int queue[T_ + 1];
    int qlen = 0, bptr = 0;
    for (int st = 0; st < T_; ++st) {
        int tr = trans[b * T_ + st];
        int mask = (tr >= 1);
        int sp1 = (qlen >= 1) ? queue[qlen - 1] : 0;
        int sp2 = (qlen >= 2) ? queue[qlen - 2] : 0;
        int bp = bptr < (N_ - 1) ? bptr : (N_ - 1);
        int o = (b * T_ + st) * 3;
        idx[o] = sp1; idx[o + 1] = sp2; idx[o + 2] = bp;
        int qlen2 = mask ? (qlen - 2 > 0 ? qlen - 2 : 0) : qlen;
        queue[qlen2] = st + 1;
        qlen = qlen2 + 1;
        bptr += mask ? 0 : 1;
    }
}

// ------------------------------------------------------------------
// Pack tree weights f16: PW[(hw*72 + k8)*512 + c], 8 K-values per uint4.
// global col C = hw*512+c = 4*j+g; g: 0=i(Ul0,Wx0) 1=o(Ul2,Wx2) 2=f(Ul1,Wx2!) 3=u(Ul3,Wx3)
// K row r: r<256 -> Ul (c-part), <512 -> Ur (h-part), <562 -> Wx (th), else 0
// ------------------------------------------------------------------
__global__ void pack_tree(const float* __restrict__ Ul, const float* __restrict__ Ur,
                          const float* __restrict__ Wx, uint4* __restrict__ PW) {
    int i = blockIdx.x * blockDim.x + threadIdx.x;
    if (i >= 2 * TREE_K8 * 512) return;
    int hw = i / (TREE_K8 * 512);
    int rem = i % (TREE_K8 * 512);
    int k8 = rem / 512, c = rem % 512;
    int C = hw * 512 + c, j = C >> 2, g = C & 3;
    const int gl[4] = {0, 2, 1, 3};
    const int gx[4] = {0, 2, 2, 3};
    unsigned short hs[8];
    for (int kk = 0; kk < 8; ++kk) {
        int r = k8 * 8 + kk;
        float v;
        if (r < 256)      v = Ul[(gl[g] * H_ + j) * H_ + r];
        else if (r < 512) v = Ur[(gl[g] * H_ + j) * H_ + (r - 256)];
        else if (r < 562) v = Wx[(gx[g] * H_ + j) * D_ + (r - 512)];
        else              v = 0.0f;
        __half h = __float2half(v);
        memcpy(&hs[kk], &h, 2);
    }
    uint4 o;
    o.x = hs[0] | ((unsigned)hs[1] << 16);
    o.y = hs[2] | ((unsigned)hs[3] << 16);
    o.z = hs[4] | ((unsigned)hs[5] << 16);
    o.w = hs[6] | ((unsigned)hs[7] << 16);
    PW[i] = o;
}

// Pack tracking weights f16: WT[k8*200 + d]; rows: <768 Wih, <818 Whh, else 0
__global__ void pack_trk(const float* __restrict__ Wih, const float* __restrict__ Whh,
                         uint4* __restrict__ WT) {
    int i = blockIdx.x * blockDim.x + threadIdx.x;
    if (i >= TRK_K8 * 200) return;
    int k8 = i / 200, d = i % 200;
    unsigned short hs[8];
    for (int kk = 0; kk < 8; ++kk) {
        int r = k8 * 8 + kk;
        float v;
        if (r < 768)      v = Wih[d * 768 + r];
        else if (r < 818) v = Whh[d * 50 + (r - 768)];
        else              v = 0.0f;
        __half h = __float2half(v);
        memcpy(&hs[kk], &h, 2);
    }
    uint4 o;
    o.x = hs[0] | ((unsigned)hs[1] << 16);
    o.y = hs[2] | ((unsigned)hs[3] << 16);
    o.z = hs[4] | ((unsigned)hs[5] << 16);
    o.w = hs[6] | ((unsigned)hs[7] << 16);
    WT[i] = o;
}

__global__ void pack_bias(const float* __restrict__ bias4, const float* __restrict__ bih,
                          const float* __restrict__ bhh,
                          float* __restrict__ bcol, float* __restrict__ btrk) {
    int i = blockIdx.x * blockDim.x + threadIdx.x;
    if (i < 1024) {
        int j = i >> 2, g = i & 3;
        const int gb[4] = {0, 2, 1, 3};
        bcol[i] = bias4[gb[g] * H_ + j];
    } else if (i < 1224) {
        int d = i - 1024;
        btrk[d] = bih[d] + bhh[d];
    }
}

// zero flags + stack row 0 (ws is re-poisoned 0xAA before every timed launch)
__global__ void init_zero(float* __restrict__ ws) {
    int i = blockIdx.x * blockDim.x + threadIdx.x;
    if (i < B_ * T_ * 2) ((int*)(ws + OFF_FLAG))[i] = 0;
    if (i < B_ * H_) {
        int b = i >> 8, j = i & 255;
        ws[OFF_SH + (size_t)b * (T_ + 1) * H_ + j] = 0.0f;
        ws[OFF_SC + (size_t)b * (T_ + 1) * H_ + j] = 0.0f;
    }
}

// ------------------------------------------------------------------
// Main: 256 WGs = 2 per batch element (column-split pair), 1024 threads.
// Pair (b, b+128) -> same XCD under round-robin dispatch (perf heuristic only).
// Stack rows + flags go through agent-scope atomics (coherent point) so the
// weight streams stay L2-cached (no acquire-invalidate).
// ------------------------------------------------------------------
__global__ __launch_bounds__(1024, 1)
void trnn_main(const float* __restrict__ tokens_h, const float* __restrict__ tokens_c,
               const int* __restrict__ trans,
               const float* __restrict__ th0, const float* __restrict__ tc0,
               float* __restrict__ ws, const int* __restrict__ idx,
               float* __restrict__ out) {
    const int b   = blockIdx.x & 127;
    const int hw  = blockIdx.x >> 7;     // which column half of the pair
    const int tid = threadIdx.x;

    float* stack_h = ws + OFF_SH + (size_t)b * (T_ + 1) * H_;
    float* stack_c = ws + OFF_SC + (size_t)b * (T_ + 1) * H_;
    const uint4* PW = (const uint4*)(ws + OFF_PW);
    const uint4* WT = (const uint4*)(ws + OFF_WTRK);
    const float* bcol = ws + OFF_BCOL;
    const float* btrk = ws + OFF_BTRK;
    int* flags = (int*)(ws + OFF_FLAG);

    __shared__ __align__(16) float avb[256];            // bt_h
    __shared__ __align__(16) float av1[576], av2[576];  // [c | h | th | pad]
    __shared__ float tc_l[50];
    __shared__ float part_t[8][200];
    __shared__ float part1[8][512], part2[8][512];
    __shared__ float act1[512], act2[512];

    // ---- init ----
    if (tid < 50) {
        tc_l[tid] = tc0[b * D_ + tid];
        float t0 = th0[b * D_ + tid];
        av1[512 + tid] = t0;
        av2[512 + tid] = t0;
    }
    if (tid >= 562 && tid < 576) { av1[tid] = 0.0f; av2[tid] = 0.0f; }
    __syncthreads();

    const float4* av1f4 = (const float4*)av1;
    const float4* av2f4 = (const float4*)av2;
    const float4* avbf4 = (const float4*)avb;

    for (int t = 1; t <= T_; ++t) {
        const int st = t - 1;
        const int i3 = (b * T_ + st) * 3;
        const int sp1 = idx[i3], sp2 = idx[i3 + 1], bp = idx[i3 + 2];

        // ---- P0: wait for partner's row t-1 ----
        if (t >= 2) {
            if (tid == 0) {
                int* f = &flags[(b * T_ + (t - 1)) * 2 + (hw ^ 1)];
                while (__hip_atomic_load(f, __ATOMIC_RELAXED, __HIP_MEMORY_SCOPE_AGENT) == 0)
                    __builtin_amdgcn_s_sleep(1);
            }
            __syncthreads();
        }

        // ---- P1: gather (coherent loads of stack rows; cached loads of tokens) ----
        {
            const int grp = tid >> 8, lane = tid & 255;
            if (grp == 0) {
                av1[lane] = aload(&stack_c[sp1 * H_ + lane]);
                avb[lane] = tokens_h[((size_t)b * N_ + bp) * H_ + lane];
            } else if (grp == 1) {
                av1[256 + lane] = aload(&stack_h[sp1 * H_ + lane]);
            } else if (grp == 2) {
                av2[lane] = aload(&stack_c[sp2 * H_ + lane]);
            } else {
                av2[256 + lane] = aload(&stack_h[sp2 * H_ + lane]);
            }
        }
        __syncthreads();

        // ---- P2: tracking LSTM partials (K = [bt_h|h1|h2|th_prev]) ----
        if (tid < 512) {
            const int ks = tid >> 6, dgrp = tid & 63;
            if (dgrp < 50) {
                float acc0 = 0.f, acc1s = 0.f, acc2s = 0.f, acc3 = 0.f;
                for (int i = 0; i < 13; ++i) {
                    const int k8 = ks * 13 + i;
                    const float4* vsrc; int kb;
                    if (k8 < 32)      { vsrc = avbf4;        kb = k8; }
                    else if (k8 < 64) { vsrc = av1f4 + 64;   kb = k8 - 32; }
                    else if (k8 < 96) { vsrc = av2f4 + 64;   kb = k8 - 64; }
                    else              { vsrc = av1f4 + 128;  kb = k8 - 96; }
                    const float4 va = vsrc[kb * 2], vb = vsrc[kb * 2 + 1];
                    const uint4* wrow = WT + k8 * 200 + dgrp;
                    #pragma unroll
                    for (int dg = 0; dg < 4; ++dg) {
                        const uint4 w = wrow[dg * 50];
                        const float2 f0 = h2f(w.x), f1 = h2f(w.y), f2 = h2f(w.z), f3 = h2f(w.w);
                        float s = fmaf(f0.x, va.x, fmaf(f0.y, va.y, fmaf(f1.x, va.z,
                                  fmaf(f1.y, va.w, fmaf(f2.x, vb.x, fmaf(f2.y, vb.y,
                                  fmaf(f3.x, vb.z, f3.y * vb.w)))))));
                        if (dg == 0) acc0 += s;
                        else if (dg == 1) acc1s += s;
                        else if (dg == 2) acc2s += s;
                        else acc3 += s;
                    }
                }
                part_t[ks][dgrp]       = acc0;
                part_t[ks][50 + dgrp]  = acc1s;
                part_t[ks][100 + dgrp] = acc2s;
                part_t[ks][150 + dgrp] = acc3;
            }
        }
        __syncthreads();

        // ---- P3: th/tc update (torch gate order i,f,g,o) ----
        if (tid < 50) {
            float g4[4];
            #pragma unroll
            for (int dg = 0; dg < 4; ++dg) {
                const int d = dg * 50 + tid;
                float s = btrk[d];
                #pragma unroll
                for (int ks = 0; ks < 8; ++ks) s += part_t[ks][d];
                g4[dg] = s;
            }
            float tcv = fmaf(sigf(g4[1]), tc_l[tid], sigf(g4[0]) * tanhf(g4[2]));
            tc_l[tid] = tcv;
            float thv = sigf(g4[3]) * tanhf(tcv);
            av1[512 + tid] = thv;
            av2[512 + tid] = thv;
        }
        __syncthreads();

        // ---- P4: tree pre-activation partials (4 cols/thread, K-split 8-way) ----
        {
            const int ks = tid >> 7, colgrp = tid & 127;
            float a1c[4] = {0.f, 0.f, 0.f, 0.f};
            float a2c[4] = {0.f, 0.f, 0.f, 0.f};
            #pragma unroll 3
            for (int i = 0; i < 9; ++i) {
                const int k8 = ks * 9 + i;
                const float4 v1a = av1f4[k8 * 2], v1b = av1f4[k8 * 2 + 1];
                const float4 v2a = av2f4[k8 * 2], v2b = av2f4[k8 * 2 + 1];
                const uint4* wrow = PW + (size_t)(hw * TREE_K8 + k8) * 512 + colgrp;
                #pragma unroll
                for (int cl = 0; cl < 4; ++cl) {
                    const uint4 w = wrow[cl * 128];
                    const float2 f0 = h2f(w.x), f1 = h2f(w.y), f2 = h2f(w.z), f3 = h2f(w.w);
                    float s1 = fmaf(f0.x, v1a.x, fmaf(f0.y, v1a.y, fmaf(f1.x, v1a.z,
                               fmaf(f1.y, v1a.w, fmaf(f2.x, v1b.x, fmaf(f2.y, v1b.y,
                               fmaf(f3.x, v1b.z, f3.y * v1b.w)))))));
                    float s2 = fmaf(f0.x, v2a.x, fmaf(f0.y, v2a.y, fmaf(f1.x, v2a.z,
                               fmaf(f1.y, v2a.w, fmaf(f2.x, v2b.x, fmaf(f2.y, v2b.y,
                               fmaf(f3.x, v2b.z, f3.y * v2b.w)))))));
                    a1c[cl] += s1;
                    a2c[cl] += s2;
                }
            }
            #pragma unroll
            for (int cl = 0; cl < 4; ++cl) {
                part1[ks][cl * 128 + colgrp] = a1c[cl];
                part2[ks][cl * 128 + colgrp] = a2c[cl];
            }
        }
        __syncthreads();

        // ---- P5: reduce + nonlinearity ----
        {
            const int c = tid & 511;
            float s = bcol[hw * 512 + c];
            if (tid < 512) {
                #pragma unroll
                for (int ks = 0; ks < 8; ++ks) s += part1[ks][c];
                act1[c] = ((c & 3) == 3) ? tanhf(s) : sigf(s);
            } else {
                #pragma unroll
                for (int ks = 0; ks < 8; ++ks) s += part2[ks][c];
                act2[c] = ((c & 3) == 3) ? tanhf(s) : sigf(s);
            }
        }
        __syncthreads();

        // ---- P6: combine + stack write (our 128 of 256 output rows) ----
        if (tid < 128) {
            const int jl = tid, j = hw * 128 + jl;
            const float i1 = act1[4 * jl], o1 = act1[4 * jl + 1], f1 = act1[4 * jl + 2], u1 = act1[4 * jl + 3];
            const float i2 = act2[4 * jl], o2 = act2[4 * jl + 1], f2 = act2[4 * jl + 2], u2 = act2[4 * jl + 3];
            // call1: c = i*u + f*c2 + f*h2 ; call2: c = i*u + f*c2 + f*h1  (faithful to source)
            const float cc1 = fmaf(i1, u1, f1 * (av2[j] + av2[256 + j]));
            const float cc2 = fmaf(i2, u2, f2 * (av2[j] + av1[256 + j]));
            const float hh1 = o1 * tanhf(cc1);
            const float hh2 = o2 * tanhf(cc2);
            const int tr = trans[b * T_ + st];
            float nh, nc;
            if (tr == 0) {
                nh = avb[j];
                nc = tokens_c[((size_t)b * N_ + bp) * H_ + j];
            } else if (tr == 1) { nh = hh1; nc = cc1; }
            else                { nh = hh2; nc = cc2; }
            astore(&stack_h[t * H_ + j], nh);
            astore(&stack_c[t * H_ + j], nc);
            if (t == T_) out[b * H_ + j] = nh;
        }
        asm volatile("s_waitcnt vmcnt(0)" ::: "memory");
        __syncthreads();
        if (tid == 0 && t < T_) {
            __hip_atomic_store(&flags[(b * T_ + t) * 2 + hw], 1,
                               __ATOMIC_RELEASE, __HIP_MEMORY_SCOPE_AGENT);
        }
    }
}

extern "C" void kernel_launch(void* const* d_in, const int* in_sizes, int n_in,
                              void* d_out, int out_size, void* d_ws, size_t ws_size,
                              hipStream_t stream) {
    (void)in_sizes; (void)n_in; (void)out_size; (void)ws_size;
    const float* tokens_h = (const float*)d_in[0];
    const float* tokens_c = (const float*)d_in[1];
    const int*   trans    = (const int*)d_in[2];
    const float* th0      = (const float*)d_in[3];
    const float* tc0      = (const float*)d_in[4];
    const float* Wx       = (const float*)d_in[5];
    const float* Ul       = (const float*)d_in[6];
    const float* Ur       = (const float*)d_in[7];
    const float* bias4    = (const float*)d_in[8];
    const float* Wih      = (const float*)d_in[9];
    const float* Whh      = (const float*)d_in[10];
    const float* bih      = (const float*)d_in[11];
    const float* bhh      = (const float*)d_in[12];

    float* ws = (float*)d_ws;
    uint4* PW   = (uint4*)(ws + OFF_PW);
    uint4* WT   = (uint4*)(ws + OFF_WTRK);
    float* bcol = ws + OFF_BCOL;
    float* btrk = ws + OFF_BTRK;
    int*   idx  = (int*)(ws + OFF_IDX);

    hipLaunchKernelGGL(init_zero, dim3(256), dim3(256), 0, stream, ws);
    hipLaunchKernelGGL(sim_idx, dim3(1), dim3(128), 0, stream, trans, idx);
    hipLaunchKernelGGL(pack_tree, dim3((2 * TREE_K8 * 512 + 255) / 256), dim3(256), 0, stream,
                       Ul, Ur, Wx, PW);
    hipLaunchKernelGGL(pack_trk, dim3((TRK_K8 * 200 + 255) / 256), dim3(256), 0, stream,
                       Wih, Whh, WT);
    hipLaunchKernelGGL(pack_bias, dim3(5), dim3(256), 0, stream, bias4, bih, bhh, bcol, btrk);
    hipLaunchKernelGGL(trnn_main, dim3(256), dim3(1024), 0, stream,
                       tokens_h, tokens_c, trans, th0, tc0, ws, idx, (float*)d_out);
}